// Round 9
// baseline (396.297 us; speedup 1.0000x reference)
//
#include <hip/hip_runtime.h>

// FromRGB fully fused + 2-tile software pipeline:
//   x[8,16,512,512] --(IHT up2 + blur down2 + Haar down2 == one separable
//   4x4 stride-2 stencil)--> new_in[8,16,256,256]  (output 0, kept in regs)
//   --(1x1 conv 16->512 * 0.25, +bias, leakyrelu(0.2)*sqrt2)--> out[8,512,256,256]
//
// Composed 1D filters (x16), [analysis][synthesis]:
//   (l,l): [1, 7, 7, 1]   (l,h): [1, 1,-1,-1]
//   (h,l): [1, 5,-5,-1]   (h,h): [1,-1,-1, 1]
//
// R9 vs R7 (R8's 512-thr + o-rotation regressed -27us -> reverted):
//  * Each block processes TWO 4-row tiles (A then B). Tile B's phase-1
//    x-loads are interleaved into tile A's conv-store stream in 4 chunks
//    (128 o-planes + 1 ch-group each) -> the grid's read traffic overlaps
//    the write drain instead of serializing before it (pay max, not sum).
//  * Grid (32,8) = 256 blocks = 1 block/CU; no o-rotation (R8 lesson:
//    concurrent blocks must hammer the same planes for page locality).
//  * Unchanged from R7: scalar-broadcast wpk weights, shfl edge cols, nt.

#define H_IN 512
#define W_IN 512
#define H_OUT 256
#define W_OUT 256
#define NB 8
#define C_MID 16
#define C_OUT 512

typedef float fx4 __attribute__((ext_vector_type(4)));

__device__ __forceinline__ float cL(int fsel, float a0, float a1, float a2, float a3) {
  return fsel == 0 ? (a0 + 7.f*a1 + 7.f*a2 + a3) : (a0 + a1 - a2 - a3);
}
__device__ __forceinline__ float cH(int fsel, float a0, float a1, float a2, float a3) {
  return fsel == 0 ? (a0 + 5.f*a1 - 5.f*a2 - a3) : (a0 - a1 - a2 + a3);
}

__device__ __forceinline__ fx4 vfma(fx4 v, float s, fx4 a) {
  a.x = fmaf(v.x, s, a.x); a.y = fmaf(v.y, s, a.y);
  a.z = fmaf(v.z, s, a.z); a.w = fmaf(v.w, s, a.w);
  return a;
}

// Prep: pack scaled weights+bias into d_ws, 32-float (128 B) stride per o:
//   wpk[o*32 + c]  = w[o][c] * sqrt2*0.25/256   (c = 0..15)
//   wpk[o*32 + 16] = bias[o] * sqrt2
__global__ __launch_bounds__(256) void k_prep(const float* __restrict__ w,
                                              const float* __restrict__ bias,
                                              float* __restrict__ wpk) {
  const int o = blockIdx.x * 256 + threadIdx.x;   // 0..511
  const float s2 = 1.41421356237309515f;
  const float wscale = s2 * 0.25f * (1.f / 256.f);
#pragma unroll
  for (int c = 0; c < 16; ++c) wpk[o * 32 + c] = w[o * 16 + c] * wscale;
  wpk[o * 32 + 16] = bias[o] * s2;
}

// Stencil for one row-visit given the two fx4 row fragments; accumulates the
// 4 components for channel ch into acc[0..3*4+ch].
#define STENCIL_VISIT(m0, m1, gY, gX, sg, p, CH, ACC)                          \
  {                                                                            \
    const float c0s = __shfl((m1).w, q - 1);                                   \
    const float c9s = __shfl((m0).x, q + 1);                                   \
    const float cc0 = (q > 0) ? c0s : 0.f;                                     \
    const float cc9 = (q < 63) ? c9s : 0.f;                                    \
    const float wl = (sg) * WL[gY][p];                                         \
    const float wh = (sg) * WH[gY][p];                                         \
    fx4 vL, vH;                                                                \
    vL.x = cL(gX, cc0,    (m0).x, (m0).y, (m0).z);                             \
    vL.y = cL(gX, (m0).y, (m0).z, (m0).w, (m1).x);                             \
    vL.z = cL(gX, (m0).w, (m1).x, (m1).y, (m1).z);                             \
    vL.w = cL(gX, (m1).y, (m1).z, (m1).w, cc9);                                \
    vH.x = cH(gX, cc0,    (m0).x, (m0).y, (m0).z);                             \
    vH.y = cH(gX, (m0).y, (m0).z, (m0).w, (m1).x);                             \
    vH.z = cH(gX, (m0).w, (m1).x, (m1).y, (m1).z);                             \
    vH.w = cH(gX, (m1).y, (m1).z, (m1).w, cc9);                                \
    ACC[0 * 4 + (CH)] = vfma(vL, wl, ACC[0 * 4 + (CH)]);                       \
    ACC[1 * 4 + (CH)] = vfma(vL, wh, ACC[1 * 4 + (CH)]);                       \
    ACC[2 * 4 + (CH)] = vfma(vH, wl, ACC[2 * 4 + (CH)]);                       \
    ACC[3 * 4 + (CH)] = vfma(vH, wh, ACC[3 * 4 + (CH)]);                       \
  }

__global__ __launch_bounds__(256, 1) void k_fused(const float* __restrict__ x,
                                                  const float* __restrict__ wpk,
                                                  float* __restrict__ nin,
                                                  float* __restrict__ out) {
  const int t = threadIdx.x;
  const int q = t & 63;                    // output cols 4q..4q+3 (wave = row)
  const int wr = t >> 6;                   // row within tile (wave-uniform)
  const int bx = blockIdx.x;               // 0..31 -> tiles 2bx, 2bx+1
  const int b  = blockIdx.y;               // image

  const float WL[2][4] = {{1.f, 7.f, 7.f, 1.f}, {1.f, 1.f, -1.f, -1.f}};
  const float WH[2][4] = {{1.f, 5.f, -5.f, -1.f}, {1.f, -1.f, -1.f, 1.f}};

  const int yA = (2 * bx) * 4 + wr;
  const int yB = (2 * bx + 1) * 4 + wr;
  const int y0A = 2 * yA - 1;
  const int y0B = 2 * yB - 1;

  fx4 accA[16], accB[16];
#pragma unroll
  for (int c = 0; c < 16; ++c) {
    accA[c] = (fx4){0.f, 0.f, 0.f, 0.f};
    accB[c] = (fx4){0.f, 0.f, 0.f, 0.f};
  }

  // ==== Phase 1 (tile A), R7-style: load + consume per row-visit ====
#pragma unroll
  for (int ch = 0; ch < 4; ++ch) {
#pragma unroll
    for (int g = 0; g < 4; ++g) {
      const int gY = g & 1, gX = g >> 1;
      const float sg = (g == 1 || g == 2) ? -1.f : 1.f;
      const float* xp = x + (size_t)(b * 16 + g * 4 + ch) * (H_IN * W_IN);
#pragma unroll
      for (int p = 0; p < 4; ++p) {
        const int yy = y0A + p;
        if (yy < 0 || yy >= H_IN) continue;   // wave-uniform branch
        const float* row = xp + (size_t)yy * W_IN + 8 * q;
        const fx4 m0 = *reinterpret_cast<const fx4*>(row);
        const fx4 m1 = *reinterpret_cast<const fx4*>(row + 4);
        STENCIL_VISIT(m0, m1, gY, gX, sg, p, ch, accA);
      }
    }
  }

  // nin stores (tile A), scaled 1/256, nontemporal.
  const float inv = 1.f / 256.f;
#pragma unroll
  for (int c = 0; c < 16; ++c) {
    fx4 r;
    r.x = accA[c].x * inv; r.y = accA[c].y * inv;
    r.z = accA[c].z * inv; r.w = accA[c].w * inv;
    __builtin_nontemporal_store(r, reinterpret_cast<fx4*>(
        nin + ((size_t)(b * C_MID + c) * H_OUT + yA) * W_OUT + 4 * q));
  }

  // ==== Interleave: tile A conv-stores (4 chunks of 128 o) with tile B
  //      phase-1 (one ch-group per chunk, loads staged in registers) ====
  float* opA = out + ((size_t)(b * C_OUT) * H_OUT + yA) * W_OUT + 4 * q;
#pragma unroll
  for (int cch = 0; cch < 4; ++cch) {
    // --- issue tile-B loads for ch=cch into staging (oldest in VMEM FIFO) ---
    fx4 s0[16], s1[16];                      // [g*4+p], static indexing only
#pragma unroll
    for (int g = 0; g < 4; ++g) {
      const float* xp = x + (size_t)(b * 16 + g * 4 + cch) * (H_IN * W_IN);
#pragma unroll
      for (int p = 0; p < 4; ++p) {
        const int yy = y0B + p;
        if (yy < H_IN) {                     // y0B >= 7, only upper edge
          const float* row = xp + (size_t)yy * W_IN + 8 * q;
          s0[g * 4 + p] = *reinterpret_cast<const fx4*>(row);
          s1[g * 4 + p] = *reinterpret_cast<const fx4*>(row + 4);
        } else {
          s0[g * 4 + p] = (fx4){0.f, 0.f, 0.f, 0.f};
          s1[g * 4 + p] = (fx4){0.f, 0.f, 0.f, 0.f};
        }
      }
    }
    // --- tile A store chunk: o in [cch*128, cch*128+128) ---
#pragma unroll 2
    for (int oi = 0; oi < 128; ++oi) {
      const int o = cch * 128 + oi;
      const float* __restrict__ wrow = wpk + (o << 5);
      const float bo = wrow[16];
      fx4 a; a.x = bo; a.y = bo; a.z = bo; a.w = bo;
#pragma unroll
      for (int c = 0; c < 16; ++c) a = vfma(accA[c], wrow[c], a);
      a.x = fmaxf(a.x, 0.2f * a.x);
      a.y = fmaxf(a.y, 0.2f * a.y);
      a.z = fmaxf(a.z, 0.2f * a.z);
      a.w = fmaxf(a.w, 0.2f * a.w);
      __builtin_nontemporal_store(a,
          reinterpret_cast<fx4*>(opA + (size_t)o * (H_OUT * W_OUT)));
    }
    // --- consume staging -> accB (ch = cch) ---
#pragma unroll
    for (int g = 0; g < 4; ++g) {
      const int gY = g & 1, gX = g >> 1;
      const float sg = (g == 1 || g == 2) ? -1.f : 1.f;
#pragma unroll
      for (int p = 0; p < 4; ++p) {
        const fx4 m0 = s0[g * 4 + p];
        const fx4 m1 = s1[g * 4 + p];
        STENCIL_VISIT(m0, m1, gY, gX, sg, p, cch, accB);
      }
    }
  }

  // nin stores (tile B).
#pragma unroll
  for (int c = 0; c < 16; ++c) {
    fx4 r;
    r.x = accB[c].x * inv; r.y = accB[c].y * inv;
    r.z = accB[c].z * inv; r.w = accB[c].w * inv;
    __builtin_nontemporal_store(r, reinterpret_cast<fx4*>(
        nin + ((size_t)(b * C_MID + c) * H_OUT + yB) * W_OUT + 4 * q));
  }

  // ==== Phase 2 (tile B), full o-loop ====
  float* opB = out + ((size_t)(b * C_OUT) * H_OUT + yB) * W_OUT + 4 * q;
#pragma unroll 2
  for (int o = 0; o < C_OUT; ++o) {
    const float* __restrict__ wrow = wpk + (o << 5);
    const float bo = wrow[16];
    fx4 a; a.x = bo; a.y = bo; a.z = bo; a.w = bo;
#pragma unroll
    for (int c = 0; c < 16; ++c) a = vfma(accB[c], wrow[c], a);
    a.x = fmaxf(a.x, 0.2f * a.x);
    a.y = fmaxf(a.y, 0.2f * a.y);
    a.z = fmaxf(a.z, 0.2f * a.z);
    a.w = fmaxf(a.w, 0.2f * a.w);
    __builtin_nontemporal_store(a,
        reinterpret_cast<fx4*>(opB + (size_t)o * (H_OUT * W_OUT)));
  }
}

extern "C" void kernel_launch(void* const* d_in, const int* in_sizes, int n_in,
                              void* d_out, int out_size, void* d_ws, size_t ws_size,
                              hipStream_t stream) {
  const float* x    = (const float*)d_in[0];
  const float* w    = (const float*)d_in[1];
  const float* bias = (const float*)d_in[2];
  float* nin = (float*)d_out;                                       // output 0
  float* out = (float*)d_out + (size_t)NB * C_MID * H_OUT * W_OUT;  // output 1
  float* wpk = (float*)d_ws;  // 512*32*4 B = 64 KB packed weight table

  k_prep<<<dim3(2), dim3(256), 0, stream>>>(w, bias, wpk);
  k_fused<<<dim3(32, 8), dim3(256), 0, stream>>>(x, wpk, nin, out);
}

// Round 10
// 280.052 us; speedup vs baseline: 1.4151x; 1.4151x over previous
//
#include <hip/hip_runtime.h>

// FromRGB fully fused:
//   x[8,16,512,512] --(IHT up2 + blur down2 + Haar down2 == one separable
//   4x4 stride-2 stencil)--> new_in[8,16,256,256]  (output 0, kept in regs)
//   --(1x1 conv 16->512 * 0.25, +bias, leakyrelu(0.2)*sqrt2)--> out[8,512,256,256]
//
// Composed 1D filters (x16), [analysis][synthesis]:
//   (l,l): [1, 7, 7, 1]   (l,h): [1, 1,-1,-1]
//   (h,l): [1, 5,-5,-1]   (h,h): [1,-1,-1, 1]
//
// R10 = R8 geometry MINUS o-rotation (deconfounding R8's two variables):
//  * 512-thread blocks, 8 rows x 256 cols -> 8 KB contiguous per
//    (block, o-plane) visit (R7: 4 KB). Grid (32,8) = 256 blocks = 1/CU,
//    8 waves/CU — occupancy identical to R7.
//  * NO o-rotation: all blocks walk planes in lockstep (R8 lesson — the
//    rotation exploded the active write footprint and thrashed DRAM pages).
//  * Unchanged from R7: scalar-broadcast wpk weights (s_load), shfl edge
//    cols, nontemporal stores.

#define H_IN 512
#define W_IN 512
#define H_OUT 256
#define W_OUT 256
#define NB 8
#define C_MID 16
#define C_OUT 512

typedef float fx4 __attribute__((ext_vector_type(4)));

__device__ __forceinline__ float cL(int fsel, float a0, float a1, float a2, float a3) {
  return fsel == 0 ? (a0 + 7.f*a1 + 7.f*a2 + a3) : (a0 + a1 - a2 - a3);
}
__device__ __forceinline__ float cH(int fsel, float a0, float a1, float a2, float a3) {
  return fsel == 0 ? (a0 + 5.f*a1 - 5.f*a2 - a3) : (a0 - a1 - a2 + a3);
}

__device__ __forceinline__ fx4 vfma(fx4 v, float s, fx4 a) {
  a.x = fmaf(v.x, s, a.x); a.y = fmaf(v.y, s, a.y);
  a.z = fmaf(v.z, s, a.z); a.w = fmaf(v.w, s, a.w);
  return a;
}

// Prep: pack scaled weights+bias into d_ws, 32-float (128 B) stride per o:
//   wpk[o*32 + c]  = w[o][c] * sqrt2*0.25/256   (c = 0..15)
//   wpk[o*32 + 16] = bias[o] * sqrt2
__global__ __launch_bounds__(256) void k_prep(const float* __restrict__ w,
                                              const float* __restrict__ bias,
                                              float* __restrict__ wpk) {
  const int o = blockIdx.x * 256 + threadIdx.x;   // 0..511
  const float s2 = 1.41421356237309515f;
  const float wscale = s2 * 0.25f * (1.f / 256.f);
#pragma unroll
  for (int c = 0; c < 16; ++c) wpk[o * 32 + c] = w[o * 16 + c] * wscale;
  wpk[o * 32 + 16] = bias[o] * s2;
}

__global__ __launch_bounds__(512) void k_fused(const float* __restrict__ x,
                                               const float* __restrict__ wpk,
                                               float* __restrict__ nin,
                                               float* __restrict__ out) {
  const int t = threadIdx.x;                  // 0..511
  const int q = t & 63;                       // output cols 4q..4q+3
  const int y = blockIdx.x * 8 + (t >> 6);    // output row (wave-uniform)
  const int b = blockIdx.y;                   // image
  const int y0 = 2 * y - 1;

  const float WL[2][4] = {{1.f, 7.f, 7.f, 1.f}, {1.f, 1.f, -1.f, -1.f}};
  const float WH[2][4] = {{1.f, 5.f, -5.f, -1.f}, {1.f, -1.f, -1.f, 1.f}};

  // ---- Phase 1: stencil. acc[comp*4+ch] = nin*256 for this thread's quad ----
  fx4 acc[16];
#pragma unroll
  for (int c = 0; c < 16; ++c) acc[c] = (fx4){0.f, 0.f, 0.f, 0.f};

#pragma unroll
  for (int ch = 0; ch < 4; ++ch) {
#pragma unroll
    for (int g = 0; g < 4; ++g) {
      const int gY = g & 1, gX = g >> 1;
      const float sg = (g == 1 || g == 2) ? -1.f : 1.f;
      const float* xp = x + (size_t)(b * 16 + g * 4 + ch) * (H_IN * W_IN);
#pragma unroll
      for (int p = 0; p < 4; ++p) {
        const int yy = y0 + p;
        if (yy < 0 || yy >= H_IN) continue;   // wave-uniform branch
        const float* row = xp + (size_t)yy * W_IN + 8 * q;
        const fx4 m0 = *reinterpret_cast<const fx4*>(row);
        const fx4 m1 = *reinterpret_cast<const fx4*>(row + 4);
        // Edge cols via neighbor lanes (wave spans the full row).
        const float c0s = __shfl(m1.w, q - 1);
        const float c9s = __shfl(m0.x, q + 1);
        const float cc0 = (q > 0) ? c0s : 0.f;
        const float cc9 = (q < 63) ? c9s : 0.f;
        const float wl = sg * WL[gY][p];
        const float wh = sg * WH[gY][p];
        fx4 vL, vH;
        vL.x = cL(gX, cc0,  m0.x, m0.y, m0.z);
        vL.y = cL(gX, m0.y, m0.z, m0.w, m1.x);
        vL.z = cL(gX, m0.w, m1.x, m1.y, m1.z);
        vL.w = cL(gX, m1.y, m1.z, m1.w, cc9);
        vH.x = cH(gX, cc0,  m0.x, m0.y, m0.z);
        vH.y = cH(gX, m0.y, m0.z, m0.w, m1.x);
        vH.z = cH(gX, m0.w, m1.x, m1.y, m1.z);
        vH.w = cH(gX, m1.y, m1.z, m1.w, cc9);
        acc[0 * 4 + ch] = vfma(vL, wl, acc[0 * 4 + ch]);
        acc[1 * 4 + ch] = vfma(vL, wh, acc[1 * 4 + ch]);
        acc[2 * 4 + ch] = vfma(vH, wl, acc[2 * 4 + ch]);
        acc[3 * 4 + ch] = vfma(vH, wh, acc[3 * 4 + ch]);
      }
    }
  }

  // nin (output 0), scaled 1/256, nontemporal (never re-read).
  const float inv = 1.f / 256.f;
#pragma unroll
  for (int c = 0; c < 16; ++c) {
    fx4 r;
    r.x = acc[c].x * inv; r.y = acc[c].y * inv;
    r.z = acc[c].z * inv; r.w = acc[c].w * inv;
    __builtin_nontemporal_store(r, reinterpret_cast<fx4*>(
        nin + ((size_t)(b * C_MID + c) * H_OUT + y) * W_OUT + 4 * q));
  }

  // ---- Phase 2: 1x1 conv; weights via wave-uniform scalar loads (s_load).
  // Plane-lockstep o-walk; 8 KB contiguous per block-visit of plane o.
  float* op = out + ((size_t)(b * C_OUT) * H_OUT + y) * W_OUT + 4 * q;
#pragma unroll 2
  for (int o = 0; o < C_OUT; ++o) {
    const float* __restrict__ wrow = wpk + (o << 5);
    const float bo = wrow[16];
    fx4 a; a.x = bo; a.y = bo; a.z = bo; a.w = bo;
#pragma unroll
    for (int c = 0; c < 16; ++c) a = vfma(acc[c], wrow[c], a);
    // sqrt2 folded into weights/bias: out = max(u, 0.2u)
    a.x = fmaxf(a.x, 0.2f * a.x);
    a.y = fmaxf(a.y, 0.2f * a.y);
    a.z = fmaxf(a.z, 0.2f * a.z);
    a.w = fmaxf(a.w, 0.2f * a.w);
    __builtin_nontemporal_store(a,
        reinterpret_cast<fx4*>(op + (size_t)o * (H_OUT * W_OUT)));
  }
}

extern "C" void kernel_launch(void* const* d_in, const int* in_sizes, int n_in,
                              void* d_out, int out_size, void* d_ws, size_t ws_size,
                              hipStream_t stream) {
  const float* x    = (const float*)d_in[0];
  const float* w    = (const float*)d_in[1];
  const float* bias = (const float*)d_in[2];
  float* nin = (float*)d_out;                                       // output 0
  float* out = (float*)d_out + (size_t)NB * C_MID * H_OUT * W_OUT;  // output 1
  float* wpk = (float*)d_ws;  // 512*32*4 B = 64 KB packed weight table

  k_prep<<<dim3(2), dim3(256), 0, stream>>>(w, bias, wpk);
  k_fused<<<dim3(32, 8), dim3(512), 0, stream>>>(x, wpk, nin, out);
}

// Round 11
// 217.833 us; speedup vs baseline: 1.8193x; 1.2856x over previous
//
#include <hip/hip_runtime.h>

// FromRGB fully fused (R11 = R7 revert + prep-kernel fold):
//   x[8,16,512,512] --(IHT up2 + blur down2 + Haar down2 == one separable
//   4x4 stride-2 stencil)--> new_in[8,16,256,256]  (output 0, kept in regs)
//   --(1x1 conv 16->512 * 0.25, +bias, leakyrelu(0.2)*sqrt2)--> out[8,512,256,256]
//
// Composed 1D filters (x16), [analysis][synthesis]:
//   (l,l): [1, 7, 7, 1]   (l,h): [1, 1,-1,-1]
//   (h,l): [1, 5,-5,-1]   (h,h): [1,-1,-1, 1]
//
// Ledger: R7 (this geometry) = 249us best. Perturbations all regress:
//   occupancy up (R2,R3 flat), no-nt (R4 -16), LDS weights (R6 -12),
//   o-rotation (R8 -27), 2-tile reg pipeline (R9 -147, VGPR bust),
//   8KB chunks (R10 -31). Keep: 256-thr/4-row blocks, 2 blocks/CU,
//   plane-lockstep o-walk, nt stores, scalar-broadcast (s_load) weights.
// R11 change: drop k_prep — read w (64B rows) + bias directly via
// wave-uniform s_load; fold 0.25/256 into acc once; apply sqrt2 after
// the activation (max is positive-homogeneous).

#define H_IN 512
#define W_IN 512
#define H_OUT 256
#define W_OUT 256
#define NB 8
#define C_MID 16
#define C_OUT 512

typedef float fx4 __attribute__((ext_vector_type(4)));

__device__ __forceinline__ float cL(int fsel, float a0, float a1, float a2, float a3) {
  return fsel == 0 ? (a0 + 7.f*a1 + 7.f*a2 + a3) : (a0 + a1 - a2 - a3);
}
__device__ __forceinline__ float cH(int fsel, float a0, float a1, float a2, float a3) {
  return fsel == 0 ? (a0 + 5.f*a1 - 5.f*a2 - a3) : (a0 - a1 - a2 + a3);
}

__device__ __forceinline__ fx4 vfma(fx4 v, float s, fx4 a) {
  a.x = fmaf(v.x, s, a.x); a.y = fmaf(v.y, s, a.y);
  a.z = fmaf(v.z, s, a.z); a.w = fmaf(v.w, s, a.w);
  return a;
}

__global__ __launch_bounds__(256) void k_fused(const float* __restrict__ x,
                                               const float* __restrict__ w,
                                               const float* __restrict__ bias,
                                               float* __restrict__ nin,
                                               float* __restrict__ out) {
  const int t = threadIdx.x;
  const int q = t & 63;                    // output cols 4q..4q+3 (wave = row)
  const int y = blockIdx.x * 4 + (t >> 6); // output row (wave-uniform)
  const int b = blockIdx.y;                // image
  const int y0 = 2 * y - 1;

  const float WL[2][4] = {{1.f, 7.f, 7.f, 1.f}, {1.f, 1.f, -1.f, -1.f}};
  const float WH[2][4] = {{1.f, 5.f, -5.f, -1.f}, {1.f, -1.f, -1.f, 1.f}};

  // ---- Phase 1: stencil. acc[comp*4+ch] = nin*256 for this thread's quad ----
  fx4 acc[16];
#pragma unroll
  for (int c = 0; c < 16; ++c) acc[c] = (fx4){0.f, 0.f, 0.f, 0.f};

#pragma unroll
  for (int ch = 0; ch < 4; ++ch) {
#pragma unroll
    for (int g = 0; g < 4; ++g) {
      const int gY = g & 1, gX = g >> 1;
      const float sg = (g == 1 || g == 2) ? -1.f : 1.f;
      const float* xp = x + (size_t)(b * 16 + g * 4 + ch) * (H_IN * W_IN);
#pragma unroll
      for (int p = 0; p < 4; ++p) {
        const int yy = y0 + p;
        if (yy < 0 || yy >= H_IN) continue;   // wave-uniform branch
        const float* row = xp + (size_t)yy * W_IN + 8 * q;
        const fx4 m0 = *reinterpret_cast<const fx4*>(row);
        const fx4 m1 = *reinterpret_cast<const fx4*>(row + 4);
        // Edge cols via neighbor lanes (wave spans the full row).
        const float c0s = __shfl(m1.w, q - 1);
        const float c9s = __shfl(m0.x, q + 1);
        const float cc0 = (q > 0) ? c0s : 0.f;
        const float cc9 = (q < 63) ? c9s : 0.f;
        const float wl = sg * WL[gY][p];
        const float wh = sg * WH[gY][p];
        fx4 vL, vH;
        vL.x = cL(gX, cc0,  m0.x, m0.y, m0.z);
        vL.y = cL(gX, m0.y, m0.z, m0.w, m1.x);
        vL.z = cL(gX, m0.w, m1.x, m1.y, m1.z);
        vL.w = cL(gX, m1.y, m1.z, m1.w, cc9);
        vH.x = cH(gX, cc0,  m0.x, m0.y, m0.z);
        vH.y = cH(gX, m0.y, m0.z, m0.w, m1.x);
        vH.z = cH(gX, m0.w, m1.x, m1.y, m1.z);
        vH.w = cH(gX, m1.y, m1.z, m1.w, cc9);
        acc[0 * 4 + ch] = vfma(vL, wl, acc[0 * 4 + ch]);
        acc[1 * 4 + ch] = vfma(vL, wh, acc[1 * 4 + ch]);
        acc[2 * 4 + ch] = vfma(vH, wl, acc[2 * 4 + ch]);
        acc[3 * 4 + ch] = vfma(vH, wh, acc[3 * 4 + ch]);
      }
    }
  }

  // nin (output 0), scaled 1/256, nontemporal (never re-read).
  const float inv = 1.f / 256.f;
#pragma unroll
  for (int c = 0; c < 16; ++c) {
    fx4 r;
    r.x = acc[c].x * inv; r.y = acc[c].y * inv;
    r.z = acc[c].z * inv; r.w = acc[c].w * inv;
    __builtin_nontemporal_store(r, reinterpret_cast<fx4*>(
        nin + ((size_t)(b * C_MID + c) * H_OUT + y) * W_OUT + 4 * q));
  }

  // Fold the conv's constant scale (0.25 * 1/256) into acc once; sqrt2 is
  // applied after the activation below (max is positive-homogeneous).
  const float cs = 0.25f * (1.f / 256.f);
#pragma unroll
  for (int c = 0; c < 16; ++c) {
    acc[c].x *= cs; acc[c].y *= cs; acc[c].z *= cs; acc[c].w *= cs;
  }

  // ---- Phase 2: 1x1 conv; weights+bias via wave-uniform scalar loads.
  // w rows are 64 B contiguous -> s_load_dwordx16; plane-lockstep o-walk;
  // 4 KB contiguous per block-visit of plane o; nt stores.
  float* op = out + ((size_t)(b * C_OUT) * H_OUT + y) * W_OUT + 4 * q;
  const float s2 = 1.41421356237309515f;
#pragma unroll 2
  for (int o = 0; o < C_OUT; ++o) {
    const float* __restrict__ wrow = w + (o << 4);
    const float bo = bias[o];
    fx4 a; a.x = bo; a.y = bo; a.z = bo; a.w = bo;
#pragma unroll
    for (int c = 0; c < 16; ++c) a = vfma(acc[c], wrow[c], a);
    // out = sqrt2 * max(v, 0.2v)
    a.x = s2 * fmaxf(a.x, 0.2f * a.x);
    a.y = s2 * fmaxf(a.y, 0.2f * a.y);
    a.z = s2 * fmaxf(a.z, 0.2f * a.z);
    a.w = s2 * fmaxf(a.w, 0.2f * a.w);
    __builtin_nontemporal_store(a,
        reinterpret_cast<fx4*>(op + (size_t)o * (H_OUT * W_OUT)));
  }
}

extern "C" void kernel_launch(void* const* d_in, const int* in_sizes, int n_in,
                              void* d_out, int out_size, void* d_ws, size_t ws_size,
                              hipStream_t stream) {
  const float* x    = (const float*)d_in[0];
  const float* w    = (const float*)d_in[1];
  const float* bias = (const float*)d_in[2];
  float* nin = (float*)d_out;                                       // output 0
  float* out = (float*)d_out + (size_t)NB * C_MID * H_OUT * W_OUT;  // output 1

  k_fused<<<dim3(64, 8), dim3(256), 0, stream>>>(x, w, bias, nin, out);
}